// Round 8
// baseline (182.810 us; speedup 1.0000x reference)
//
#include <hip/hip_runtime.h>
#include <hip/hip_bf16.h>
#include <stdint.h>

typedef __attribute__((ext_vector_type(8))) short bf16x8;
typedef __attribute__((ext_vector_type(4))) float f32x4;

#define LN_EPS 1e-5f

// ---------------- helpers ----------------
__device__ inline unsigned f2bf(float f) {
    unsigned u = __builtin_bit_cast(unsigned, f);
    u += 0x7fffu + ((u >> 16) & 1u);          // RNE
    return u >> 16;
}
__device__ inline float bf2f(unsigned u) {
    return __builtin_bit_cast(float, u << 16);
}
__device__ inline float sigf(float x) {
    return 1.0f / (1.0f + __expf(-x));
}
__device__ inline float tanh_fast(float x) {
    return __builtin_fmaf(2.0f, 1.0f / (1.0f + __expf(-2.0f * x)), -1.0f);
}
__device__ inline float wred(float v) {
#pragma unroll
    for (int o = 32; o > 0; o >>= 1) v += __shfl_xor(v, o);
    return v;
}
__device__ inline void gload_lds16(const void* g, void* l) {
    __builtin_amdgcn_global_load_lds(
        (const __attribute__((address_space(1))) void*)g,
        (__attribute__((address_space(3))) void*)l, 16, 0, 0);
}

// ---------------- merged cast f32 -> bf16 (4 regions, 1 launch) ----------------
__global__ __launch_bounds__(256) void cast_all(
    const float4* __restrict__ s0, ushort4* __restrict__ d0, int n0,
    const float4* __restrict__ s1, ushort4* __restrict__ d1, int n1,
    const float4* __restrict__ s2, ushort4* __restrict__ d2, int n2,
    const float4* __restrict__ s3, ushort4* __restrict__ d3, int n3)
{
    int j = blockIdx.x * blockDim.x + threadIdx.x;
    const float4* s; ushort4* d;
    if (j < n0) { s = s0; d = d0; }
    else {
        j -= n0;
        if (j < n1) { s = s1; d = d1; }
        else {
            j -= n1;
            if (j < n2) { s = s2; d = d2; }
            else {
                j -= n2;
                if (j >= n3) return;
                s = s3; d = d3;
            }
        }
    }
    float4 v = s[j];
    ushort4 o;
    o.x = (unsigned short)f2bf(v.x); o.y = (unsigned short)f2bf(v.y);
    o.z = (unsigned short)f2bf(v.z); o.w = (unsigned short)f2bf(v.w);
    d[j] = o;
}

// =====================================================================
// 256x256 bf16 NT GEMM (R4 K-loop: ring-4 LDS, counted vmcnt, setprio,
// XOR chunk swizzle, bijective XCD swizzle over 512 blocks).
// Swapped-operand MFMA: acc[f][n] = mfma(W[f], X[n]).
// NEW epilogue: C stored in BLOCKED layout so every store instr is 1 KB
// fully coalesced:
//   piece(by,bx,w,n,f2) = 1024 B, lane (kc*16+lr) owns 16 B at lane*16:
//     [f&1 (8B)][e (2B x4)]  for f = 2*f2, 2*f2+1
//   ushort offset = ((((by*16+bx)*8 + w)*4 + n)*4 + f2)*512 + lane*8
// ln_lstm regathers via global_load_lds + conflict-free ds_read_b64.
// =====================================================================
#define GNT 32   // K/32

__global__ __launch_bounds__(512) void gemm8p(
    const short* __restrict__ Aa, const short* __restrict__ Ba, unsigned short* __restrict__ Ca,
    const short* __restrict__ Ab, const short* __restrict__ Bb, unsigned short* __restrict__ Cb,
    const float* __restrict__ Bias,   // b_hh, used when z==1
    float2* __restrict__ P,           // [2][Bn][32] per-row partials (bx*2+wr)
    int N, int K, int Bn)
{
    __shared__ __attribute__((aligned(16))) short lds[65536];  // 128 KiB
    short* ldsA = lds;
    short* ldsB = lds + 32768;

    // ---- bijective XCD swizzle over 512 blocks ----
    const int gx  = gridDim.x;            // 16
    const int gxy = gx * gridDim.y;       // 256
    int bid = (blockIdx.z * gridDim.y + blockIdx.y) * gx + blockIdx.x;
    const int cpx = (gxy * gridDim.z) >> 3;   // 64
    int swz = (bid & 7) * cpx + (bid >> 3);
    const int z  = swz / gxy;
    const int r2 = swz - z * gxy;
    const int by = r2 / gx;
    const int bx = r2 - by * gx;

    const short* __restrict__ A = z ? Ab : Aa;   // batch [Bn,K]
    const short* __restrict__ B = z ? Bb : Ba;   // weights [N,K]
    unsigned short* __restrict__ C = z ? Cb : Ca;
    const int brow = by * 256, bcol = bx * 256;

    const int t    = threadIdx.x;
    const int lane = t & 63, w = t >> 6;
    const int wr = w >> 2, wc = w & 3;    // wr: gate half (128), wc: batch quarter (64)
    const int lr = lane & 15, kc = lane >> 4;

    // ---- staging addresses ----
    const int ci0 = t, ci1 = t + 512;
    const int r0 = ci0 >> 2, l0 = (ci0 & 3) ^ ((r0 >> 1) & 3);
    const int r1 = ci1 >> 2, l1 = (ci1 & 3) ^ ((r1 >> 1) & 3);
    const int gA0 = (brow + r0) * K + l0 * 8;
    const int gA1 = (brow + r1) * K + l1 * 8;
    const int gB0 = (bcol + r0) * K + l0 * 8;
    const int gB1 = (bcol + r1) * K + l1 * 8;
    const int d0 = ci0 * 8, d1 = ci1 * 8;

#define STAGE_A(u) { const int so_ = ((u) & 3) * 8192; \
    gload_lds16(A + gA0 + (u) * 32, ldsA + so_ + d0);  \
    gload_lds16(A + gA1 + (u) * 32, ldsA + so_ + d1); }
#define STAGE_B(u) { const int so_ = ((u) & 3) * 8192; \
    gload_lds16(B + gB0 + (u) * 32, ldsB + so_ + d0);  \
    gload_lds16(B + gB1 + (u) * 32, ldsB + so_ + d1); }

    // ---- ds_read offsets: W-frags (weights, 8) and X-frags (batch, 4) ----
    int offW[8], offX[4];
#pragma unroll
    for (int f = 0; f < 8; ++f) {
        int r = wr * 128 + f * 16 + lr;
        offW[f] = r * 32 + ((kc ^ ((r >> 1) & 3)) * 8);
    }
#pragma unroll
    for (int n = 0; n < 4; ++n) {
        int r = wc * 64 + n * 16 + lr;
        offX[n] = r * 32 + ((kc ^ ((r >> 1) & 3)) * 8);
    }

    f32x4 acc[8][4];
#pragma unroll
    for (int i = 0; i < 8; ++i)
#pragma unroll
        for (int j = 0; j < 4; ++j)
            acc[i][j] = (f32x4){0.f, 0.f, 0.f, 0.f};

    STAGE_A(0); STAGE_B(0); STAGE_A(1); STAGE_B(1); STAGE_A(2);
    asm volatile("s_waitcnt vmcnt(6)" ::: "memory");
    __builtin_amdgcn_s_barrier();

#pragma unroll 4
    for (int T = 0; T < GNT; ++T) {
        const int so = (T & 3) * 8192;
        bf16x8 w0, w1, w2, w3, x0, x1, x2, x3;

        // ---- phase 0: W-frags 0-3 x all X ----
        w0 = *(const bf16x8*)&ldsB[so + offW[0]];
        w1 = *(const bf16x8*)&ldsB[so + offW[1]];
        w2 = *(const bf16x8*)&ldsB[so + offW[2]];
        w3 = *(const bf16x8*)&ldsB[so + offW[3]];
        x0 = *(const bf16x8*)&ldsA[so + offX[0]];
        x1 = *(const bf16x8*)&ldsA[so + offX[1]];
        x2 = *(const bf16x8*)&ldsA[so + offX[2]];
        x3 = *(const bf16x8*)&ldsA[so + offX[3]];
        if (T + 2 < GNT) STAGE_B(T + 2);
        __builtin_amdgcn_s_barrier();
        asm volatile("s_waitcnt lgkmcnt(0)" ::: "memory");
        __builtin_amdgcn_sched_barrier(0);
        __builtin_amdgcn_s_setprio(1);
        acc[0][0] = __builtin_amdgcn_mfma_f32_16x16x32_bf16(w0, x0, acc[0][0], 0, 0, 0);
        acc[0][1] = __builtin_amdgcn_mfma_f32_16x16x32_bf16(w0, x1, acc[0][1], 0, 0, 0);
        acc[0][2] = __builtin_amdgcn_mfma_f32_16x16x32_bf16(w0, x2, acc[0][2], 0, 0, 0);
        acc[0][3] = __builtin_amdgcn_mfma_f32_16x16x32_bf16(w0, x3, acc[0][3], 0, 0, 0);
        acc[1][0] = __builtin_amdgcn_mfma_f32_16x16x32_bf16(w1, x0, acc[1][0], 0, 0, 0);
        acc[1][1] = __builtin_amdgcn_mfma_f32_16x16x32_bf16(w1, x1, acc[1][1], 0, 0, 0);
        acc[1][2] = __builtin_amdgcn_mfma_f32_16x16x32_bf16(w1, x2, acc[1][2], 0, 0, 0);
        acc[1][3] = __builtin_amdgcn_mfma_f32_16x16x32_bf16(w1, x3, acc[1][3], 0, 0, 0);
        acc[2][0] = __builtin_amdgcn_mfma_f32_16x16x32_bf16(w2, x0, acc[2][0], 0, 0, 0);
        acc[2][1] = __builtin_amdgcn_mfma_f32_16x16x32_bf16(w2, x1, acc[2][1], 0, 0, 0);
        acc[2][2] = __builtin_amdgcn_mfma_f32_16x16x32_bf16(w2, x2, acc[2][2], 0, 0, 0);
        acc[2][3] = __builtin_amdgcn_mfma_f32_16x16x32_bf16(w2, x3, acc[2][3], 0, 0, 0);
        acc[3][0] = __builtin_amdgcn_mfma_f32_16x16x32_bf16(w3, x0, acc[3][0], 0, 0, 0);
        acc[3][1] = __builtin_amdgcn_mfma_f32_16x16x32_bf16(w3, x1, acc[3][1], 0, 0, 0);
        acc[3][2] = __builtin_amdgcn_mfma_f32_16x16x32_bf16(w3, x2, acc[3][2], 0, 0, 0);
        acc[3][3] = __builtin_amdgcn_mfma_f32_16x16x32_bf16(w3, x3, acc[3][3], 0, 0, 0);
        __builtin_amdgcn_s_setprio(0);
        __builtin_amdgcn_s_barrier();

        // ---- phase 1: W-frags 4-7 x all X ----
        w0 = *(const bf16x8*)&ldsB[so + offW[4]];
        w1 = *(const bf16x8*)&ldsB[so + offW[5]];
        w2 = *(const bf16x8*)&ldsB[so + offW[6]];
        w3 = *(const bf16x8*)&ldsB[so + offW[7]];
        if (T + 3 < GNT) STAGE_A(T + 3);
        __builtin_amdgcn_s_barrier();
        asm volatile("s_waitcnt lgkmcnt(0)" ::: "memory");
        __builtin_amdgcn_sched_barrier(0);
        __builtin_amdgcn_s_setprio(1);
        acc[4][0] = __builtin_amdgcn_mfma_f32_16x16x32_bf16(w0, x0, acc[4][0], 0, 0, 0);
        acc[4][1] = __builtin_amdgcn_mfma_f32_16x16x32_bf16(w0, x1, acc[4][1], 0, 0, 0);
        acc[4][2] = __builtin_amdgcn_mfma_f32_16x16x32_bf16(w0, x2, acc[4][2], 0, 0, 0);
        acc[4][3] = __builtin_amdgcn_mfma_f32_16x16x32_bf16(w0, x3, acc[4][3], 0, 0, 0);
        acc[5][0] = __builtin_amdgcn_mfma_f32_16x16x32_bf16(w1, x0, acc[5][0], 0, 0, 0);
        acc[5][1] = __builtin_amdgcn_mfma_f32_16x16x32_bf16(w1, x1, acc[5][1], 0, 0, 0);
        acc[5][2] = __builtin_amdgcn_mfma_f32_16x16x32_bf16(w1, x2, acc[5][2], 0, 0, 0);
        acc[5][3] = __builtin_amdgcn_mfma_f32_16x16x32_bf16(w1, x3, acc[5][3], 0, 0, 0);
        acc[6][0] = __builtin_amdgcn_mfma_f32_16x16x32_bf16(w2, x0, acc[6][0], 0, 0, 0);
        acc[6][1] = __builtin_amdgcn_mfma_f32_16x16x32_bf16(w2, x1, acc[6][1], 0, 0, 0);
        acc[6][2] = __builtin_amdgcn_mfma_f32_16x16x32_bf16(w2, x2, acc[6][2], 0, 0, 0);
        acc[6][3] = __builtin_amdgcn_mfma_f32_16x16x32_bf16(w2, x3, acc[6][3], 0, 0, 0);
        acc[7][0] = __builtin_amdgcn_mfma_f32_16x16x32_bf16(w3, x0, acc[7][0], 0, 0, 0);
        acc[7][1] = __builtin_amdgcn_mfma_f32_16x16x32_bf16(w3, x1, acc[7][1], 0, 0, 0);
        acc[7][2] = __builtin_amdgcn_mfma_f32_16x16x32_bf16(w3, x2, acc[7][2], 0, 0, 0);
        acc[7][3] = __builtin_amdgcn_mfma_f32_16x16x32_bf16(w3, x3, acc[7][3], 0, 0, 0);
        __builtin_amdgcn_s_setprio(0);
        if (T < GNT - 3)      { asm volatile("s_waitcnt vmcnt(6)" ::: "memory"); }
        else if (T == GNT - 3){ asm volatile("s_waitcnt vmcnt(4)" ::: "memory"); }
        else if (T == GNT - 2){ asm volatile("s_waitcnt vmcnt(0)" ::: "memory"); }
        __builtin_amdgcn_s_barrier();
    }

    // ---- epilogue: bias, pack to bf16, in-lane stats ----
    const int gc0 = bcol + wr * 128 + kc * 4;
    const int mr0 = brow + wc * 64 + lr;

    float4 bias4[8];
#pragma unroll
    for (int f = 0; f < 8; ++f) {
        if (z) bias4[f] = *reinterpret_cast<const float4*>(&Bias[gc0 + f * 16]);
        else   bias4[f] = (float4){0.f, 0.f, 0.f, 0.f};
    }

    uint2 pk[8][4];
    float s[4] = {0.f, 0.f, 0.f, 0.f}, q[4] = {0.f, 0.f, 0.f, 0.f};
#pragma unroll
    for (int f = 0; f < 8; ++f) {
#pragma unroll
        for (int n = 0; n < 4; ++n) {
            float v0 = acc[f][n][0] + bias4[f].x;
            float v1 = acc[f][n][1] + bias4[f].y;
            float v2 = acc[f][n][2] + bias4[f].z;
            float v3 = acc[f][n][3] + bias4[f].w;
            unsigned u0 = f2bf(v0), u1 = f2bf(v1), u2 = f2bf(v2), u3 = f2bf(v3);
            float e0 = bf2f(u0), e1 = bf2f(u1), e2 = bf2f(u2), e3 = bf2f(u3);
            s[n] += (e0 + e1) + (e2 + e3);
            q[n] += (e0 * e0 + e1 * e1) + (e2 * e2 + e3 * e3);
            pk[f][n].x = u0 | (u1 << 16);
            pk[f][n].y = u2 | (u3 << 16);
        }
    }
#pragma unroll
    for (int n = 0; n < 4; ++n) {
        s[n] += __shfl_xor(s[n], 16); s[n] += __shfl_xor(s[n], 32);
        q[n] += __shfl_xor(q[n], 16); q[n] += __shfl_xor(q[n], 32);
    }
    if (kc == 0) {
#pragma unroll
        for (int n = 0; n < 4; ++n) {
            float2 pr; pr.x = s[n]; pr.y = q[n];
            P[(size_t)(z * Bn + mr0 + n * 16) * 32 + bx * 2 + wr] = pr;
        }
    }

    // ---- blocked-layout C stores: 16 x dwordx4, each instr 1 KB coalesced ----
#pragma unroll
    for (int n = 0; n < 4; ++n) {
#pragma unroll
        for (int f2 = 0; f2 < 4; ++f2) {
            uint4 v;
            v.x = pk[2 * f2][n].x;     v.y = pk[2 * f2][n].y;
            v.z = pk[2 * f2 + 1][n].x; v.w = pk[2 * f2 + 1][n].y;
            const size_t uso = ((size_t)((((by * 16 + bx) * 8 + w) * 4 + n) * 4 + f2)) * 512 + lane * 8;
            *reinterpret_cast<uint4*>(&C[uso]) = v;
        }
    }
#undef STAGE_A
#undef STAGE_B
}

// ---------------- single-pass LN + LSTM pointwise (blocked-layout input) ----------------
__global__ __launch_bounds__(256) void ln_lstm(
    const unsigned short* __restrict__ i2hL,  // blocked layout (see gemm epilogue)
    const unsigned short* __restrict__ h2hL,
    const float* __restrict__ cx,
    const float2* __restrict__ P,             // [2][B][32] partial (sum,sumsq)
    const float* __restrict__ g_ih, const float* __restrict__ be_ih,
    const float* __restrict__ g_hh, const float* __restrict__ be_hh,
    const float* __restrict__ g_ho, const float* __restrict__ be_ho,
    float* __restrict__ hy, float* __restrict__ cy, int H, int B)
{
    const int b = blockIdx.x;
    const int t = threadIdx.x;
    const int lane = t & 63;
    const int wave = t >> 6;
    const int H4 = 4 * H;

    // decompose batch row
    const int by = b >> 8, wc = (b >> 6) & 3, n = (b >> 4) & 3, lr = b & 15;

    __shared__ __attribute__((aligned(16))) unsigned short g8[8192];  // 16 KB row gather
    __shared__ float red[4][2];
    __shared__ float st[4];   // mI, rI, mH, rH

    // ---- stage this row's 1024 x 16B pieces (both matrices) into LDS ----
#pragma unroll
    for (int k = 0; k < 4; ++k) {
        const int qp = t + k * 256;            // piece id 0..1023
        const int mt = qp >> 9;
        const int r  = qp & 511;
        const int c  = r >> 2;                  // bx*8 + wr*4 + kc
        const int f2 = r & 3;
        const int bxg = c >> 3, wrg = (c >> 2) & 1, kcg = c & 3;
        const unsigned short* mat = mt ? h2hL : i2hL;
        const size_t uso = ((size_t)((((by * 16 + bxg) * 8 + (wrg * 4 + wc)) * 4 + n) * 4 + f2)) * 512
                         + (kcg * 16 + lr) * 8;
        gload_lds16(mat + uso, g8 + (size_t)qp * 8);
    }

    // ---- fold the 32 col-block partials for this row (both matrices), wave 0 ----
    if (wave == 0) {
        const int half = lane >> 5;               // 0: i2h, 1: h2h
        float2 v = P[((size_t)half * B + b) * 32 + (lane & 31)];
        v.x += __shfl_xor(v.x, 1);  v.y += __shfl_xor(v.y, 1);
        v.x += __shfl_xor(v.x, 2);  v.y += __shfl_xor(v.y, 2);
        v.x += __shfl_xor(v.x, 4);  v.y += __shfl_xor(v.y, 4);
        v.x += __shfl_xor(v.x, 8);  v.y += __shfl_xor(v.y, 8);
        v.x += __shfl_xor(v.x, 16); v.y += __shfl_xor(v.y, 16);
        if ((lane & 31) == 0) {
            const float inv4H = 1.0f / (float)H4;
            float m = v.x * inv4H;
            float r = rsqrtf(v.y * inv4H - m * m + LN_EPS);
            st[half * 2]     = m;
            st[half * 2 + 1] = r;
        }
    }
    __syncthreads();   // drains gload_lds (vmcnt) + publishes st
    const float mI = st[0], rI = st[1], mH = st[2], rH = st[3];

    const int h0 = t * 4;
    float gate[4][4];
#pragma unroll
    for (int qd = 0; qd < 4; ++qd) {
        const int g = qd * 1024 + h0;           // 4 consecutive gates, g%4==0
        const int c = (g >> 8) * 8 + ((g >> 7) & 1) * 4 + ((g >> 2) & 3);
        const int f = (g >> 4) & 7;
        const int widx = (c * 4 + (f >> 1)) * 8 + (f & 1) * 4;   // ushort index
        uint2 vi2 = *reinterpret_cast<const uint2*>(&g8[widx]);
        uint2 vh2 = *reinterpret_cast<const uint2*>(&g8[4096 + widx]);
        const int j = qd * H + h0;
        float4 gi = *reinterpret_cast<const float4*>(&g_ih[j]);
        float4 bi = *reinterpret_cast<const float4*>(&be_ih[j]);
        float4 gh = *reinterpret_cast<const float4*>(&g_hh[j]);
        float4 bh = *reinterpret_cast<const float4*>(&be_hh[j]);
        float xi0 = bf2f(vi2.x & 0xffffu), xi1 = bf2f(vi2.x >> 16);
        float xi2 = bf2f(vi2.y & 0xffffu), xi3 = bf2f(vi2.y >> 16);
        float xh0 = bf2f(vh2.x & 0xffffu), xh1 = bf2f(vh2.x >> 16);
        float xh2 = bf2f(vh2.y & 0xffffu), xh3 = bf2f(vh2.y >> 16);
        gate[qd][0] = (xi0 - mI) * rI * gi.x + bi.x + (xh0 - mH) * rH * gh.x + bh.x;
        gate[qd][1] = (xi1 - mI) * rI * gi.y + bi.y + (xh1 - mH) * rH * gh.y + bh.y;
        gate[qd][2] = (xi2 - mI) * rI * gi.z + bi.z + (xh2 - mH) * rH * gh.z + bh.z;
        gate[qd][3] = (xi3 - mI) * rI * gi.w + bi.w + (xh3 - mH) * rH * gh.w + bh.w;
    }

    float4 cxv = *reinterpret_cast<const float4*>(&cx[(size_t)b * H + h0]);
    float cvals[4] = {cxv.x, cxv.y, cxv.z, cxv.w};
    float tv[4], ov[4];
    float s2 = 0.f, q2 = 0.f;
    float4 cyv;
#pragma unroll
    for (int k = 0; k < 4; ++k) {
        float c = sigf(gate[1][k]) * cvals[k] + sigf(gate[0][k]) * tanh_fast(gate[3][k]);
        ((float*)&cyv)[k] = c;
        float tc = tanh_fast(c);
        tv[k] = tc; ov[k] = sigf(gate[2][k]);
        s2 += tc; q2 += tc * tc;
    }
    *reinterpret_cast<float4*>(&cy[(size_t)b * H + h0]) = cyv;

    s2 = wred(s2); q2 = wred(q2);
    if (lane == 0) { red[wave][0] = s2; red[wave][1] = q2; }
    __syncthreads();
    float S2 = red[0][0] + red[1][0] + red[2][0] + red[3][0];
    float Q2 = red[0][1] + red[1][1] + red[2][1] + red[3][1];
    const float invH = 1.0f / (float)H;
    float mt2 = S2 * invH;
    float rt = rsqrtf(Q2 * invH - mt2 * mt2 + LN_EPS);

    float4 go = *reinterpret_cast<const float4*>(&g_ho[h0]);
    float4 bo = *reinterpret_cast<const float4*>(&be_ho[h0]);
    float4 hyv;
    hyv.x = ov[0] * ((tv[0] - mt2) * rt * go.x + bo.x);
    hyv.y = ov[1] * ((tv[1] - mt2) * rt * go.y + bo.y);
    hyv.z = ov[2] * ((tv[2] - mt2) * rt * go.z + bo.z);
    hyv.w = ov[3] * ((tv[3] - mt2) * rt * go.w + bo.w);
    *reinterpret_cast<float4*>(&hy[(size_t)b * H + h0]) = hyv;
}

// ---------------- launcher ----------------
extern "C" void kernel_launch(void* const* d_in, const int* in_sizes, int n_in,
                              void* d_out, int out_size, void* d_ws, size_t ws_size,
                              hipStream_t stream) {
    const float* inputs  = (const float*)d_in[0];
    const float* hx      = (const float*)d_in[1];
    const float* cx      = (const float*)d_in[2];
    const float* w_ih    = (const float*)d_in[3];
    const float* w_hh    = (const float*)d_in[4];
    const float* b_hh    = (const float*)d_in[5];
    const float* g_ih    = (const float*)d_in[6];
    const float* beta_ih = (const float*)d_in[7];
    const float* g_hh    = (const float*)d_in[8];
    const float* beta_hh = (const float*)d_in[9];
    const float* g_ho    = (const float*)d_in[10];
    const float* beta_ho = (const float*)d_in[11];

    const int H  = in_sizes[10];            // 1024
    const int B  = in_sizes[1] / H;         // 4096
    const int D  = in_sizes[0] / B;         // 1024
    const int H4 = 4 * H;

    uint8_t* ws = (uint8_t*)d_ws;
    size_t off = 0;
    short* Abf  = (short*)(ws + off); off += (size_t)B * D * 2;
    short* Hbf  = (short*)(ws + off); off += (size_t)B * H * 2;
    short* Wih  = (short*)(ws + off); off += (size_t)H4 * D * 2;
    short* Whh  = (short*)(ws + off); off += (size_t)H4 * H * 2;
    unsigned short* i2hb = (unsigned short*)(ws + off); off += (size_t)B * H4 * 2;
    unsigned short* h2hb = (unsigned short*)(ws + off); off += (size_t)B * H4 * 2;
    float2* P   = (float2*)(ws + off); off += (size_t)2 * B * 32 * sizeof(float2);

    float* hy  = (float*)d_out;
    float* cyo = (float*)d_out + (size_t)B * H;

    // 1) all casts in one launch
    {
        const int n0 = (B * D) / 4, n1 = (B * H) / 4, n2 = (H4 * D) / 4, n3 = (H4 * H) / 4;
        const int tot = n0 + n1 + n2 + n3;
        cast_all<<<(tot + 255) / 256, 256, 0, stream>>>(
            (const float4*)inputs, (ushort4*)Abf, n0,
            (const float4*)hx,     (ushort4*)Hbf, n1,
            (const float4*)w_ih,   (ushort4*)Wih, n2,
            (const float4*)w_hh,   (ushort4*)Whh, n3);
    }

    // 2) both GEMMs + fused LN-stats partials, blocked C layout
    {
        dim3 grid(H4 / 256, B / 256, 2);
        gemm8p<<<grid, 512, 0, stream>>>(Abf, Wih, i2hb, Hbf, Whh, h2hb, b_hh, P, H4, D, B);
    }

    // 3) single-pass LN + LSTM (folds partials itself, regathers blocked layout)
    ln_lstm<<<B, 256, 0, stream>>>(i2hb, h2hb, cx, P,
                                   g_ih, beta_ih, g_hh, beta_hh, g_ho, beta_ho,
                                   hy, cyo, H, B);
}

// Round 9
// 128.732 us; speedup vs baseline: 1.4201x; 1.4201x over previous
//
#include <hip/hip_runtime.h>
#include <hip/hip_bf16.h>
#include <stdint.h>

typedef __attribute__((ext_vector_type(8))) short bf16x8;
typedef __attribute__((ext_vector_type(4))) float f32x4;

#define LN_EPS 1e-5f

// ---------------- helpers ----------------
__device__ inline unsigned f2bf(float f) {
    unsigned u = __builtin_bit_cast(unsigned, f);
    u += 0x7fffu + ((u >> 16) & 1u);          // RNE
    return u >> 16;
}
__device__ inline float bf2f(unsigned u) {
    return __builtin_bit_cast(float, u << 16);
}
__device__ inline float sigf(float x) {
    return 1.0f / (1.0f + __expf(-x));
}
__device__ inline float tanh_fast(float x) {
    return __builtin_fmaf(2.0f, 1.0f / (1.0f + __expf(-2.0f * x)), -1.0f);
}
__device__ inline float wred(float v) {
#pragma unroll
    for (int o = 32; o > 0; o >>= 1) v += __shfl_xor(v, o);
    return v;
}
__device__ inline void gload_lds16(const void* g, void* l) {
    __builtin_amdgcn_global_load_lds(
        (const __attribute__((address_space(1))) void*)g,
        (__attribute__((address_space(3))) void*)l, 16, 0, 0);
}

// ---------------- merged cast f32 -> bf16 (4 regions, 1 launch) ----------------
__global__ __launch_bounds__(256) void cast_all(
    const float4* __restrict__ s0, ushort4* __restrict__ d0, int n0,
    const float4* __restrict__ s1, ushort4* __restrict__ d1, int n1,
    const float4* __restrict__ s2, ushort4* __restrict__ d2, int n2,
    const float4* __restrict__ s3, ushort4* __restrict__ d3, int n3)
{
    int j = blockIdx.x * blockDim.x + threadIdx.x;
    const float4* s; ushort4* d;
    if (j < n0) { s = s0; d = d0; }
    else {
        j -= n0;
        if (j < n1) { s = s1; d = d1; }
        else {
            j -= n1;
            if (j < n2) { s = s2; d = d2; }
            else {
                j -= n2;
                if (j >= n3) return;
                s = s3; d = d3;
            }
        }
    }
    float4 v = s[j];
    ushort4 o;
    o.x = (unsigned short)f2bf(v.x); o.y = (unsigned short)f2bf(v.y);
    o.z = (unsigned short)f2bf(v.z); o.w = (unsigned short)f2bf(v.w);
    d[j] = o;
}

// =====================================================================
// 256x256 bf16 NT GEMM (R4 K-loop: ring-4 LDS, counted vmcnt, setprio,
// XOR chunk swizzle, bijective XCD swizzle over 512 blocks).
// Swapped-operand MFMA: acc[f][n] = mfma(W[f], X[n]) -> lane holds 4
// consecutive gate cols at one batch row.
// SLIM epilogue: pack to bf16 + uint2 row-major store ONLY. All LN/bias
// math moved to ln_lstm (memory-bound, 16 blocks/CU -> VALU is free there).
// =====================================================================
#define GNT 32   // K/32

__global__ __launch_bounds__(512) void gemm8p(
    const short* __restrict__ Aa, const short* __restrict__ Ba, unsigned short* __restrict__ Ca,
    const short* __restrict__ Ab, const short* __restrict__ Bb, unsigned short* __restrict__ Cb,
    int N, int K)
{
    __shared__ __attribute__((aligned(16))) short lds[65536];  // 128 KiB
    short* ldsA = lds;
    short* ldsB = lds + 32768;

    // ---- bijective XCD swizzle over 512 blocks ----
    const int gx  = gridDim.x;            // 16
    const int gxy = gx * gridDim.y;       // 256
    int bid = (blockIdx.z * gridDim.y + blockIdx.y) * gx + blockIdx.x;
    const int cpx = (gxy * gridDim.z) >> 3;   // 64
    int swz = (bid & 7) * cpx + (bid >> 3);
    const int z  = swz / gxy;
    const int r2 = swz - z * gxy;
    const int by = r2 / gx;
    const int bx = r2 - by * gx;

    const short* __restrict__ A = z ? Ab : Aa;   // batch [M,K]
    const short* __restrict__ B = z ? Bb : Ba;   // weights [N,K]
    unsigned short* __restrict__ C = z ? Cb : Ca;
    const int brow = by * 256, bcol = bx * 256;

    const int t    = threadIdx.x;
    const int lane = t & 63, w = t >> 6;
    const int wr = w >> 2, wc = w & 3;    // wr: gate half (128), wc: batch quarter (64)
    const int lr = lane & 15, kc = lane >> 4;

    // ---- staging addresses ----
    const int ci0 = t, ci1 = t + 512;
    const int r0 = ci0 >> 2, l0 = (ci0 & 3) ^ ((r0 >> 1) & 3);
    const int r1 = ci1 >> 2, l1 = (ci1 & 3) ^ ((r1 >> 1) & 3);
    const int gA0 = (brow + r0) * K + l0 * 8;
    const int gA1 = (brow + r1) * K + l1 * 8;
    const int gB0 = (bcol + r0) * K + l0 * 8;
    const int gB1 = (bcol + r1) * K + l1 * 8;
    const int d0 = ci0 * 8, d1 = ci1 * 8;

#define STAGE_A(u) { const int so_ = ((u) & 3) * 8192; \
    gload_lds16(A + gA0 + (u) * 32, ldsA + so_ + d0);  \
    gload_lds16(A + gA1 + (u) * 32, ldsA + so_ + d1); }
#define STAGE_B(u) { const int so_ = ((u) & 3) * 8192; \
    gload_lds16(B + gB0 + (u) * 32, ldsB + so_ + d0);  \
    gload_lds16(B + gB1 + (u) * 32, ldsB + so_ + d1); }

    // ---- ds_read offsets: W-frags (weights, 8) and X-frags (batch, 4) ----
    int offW[8], offX[4];
#pragma unroll
    for (int f = 0; f < 8; ++f) {
        int r = wr * 128 + f * 16 + lr;
        offW[f] = r * 32 + ((kc ^ ((r >> 1) & 3)) * 8);
    }
#pragma unroll
    for (int n = 0; n < 4; ++n) {
        int r = wc * 64 + n * 16 + lr;
        offX[n] = r * 32 + ((kc ^ ((r >> 1) & 3)) * 8);
    }

    f32x4 acc[8][4];
#pragma unroll
    for (int i = 0; i < 8; ++i)
#pragma unroll
        for (int j = 0; j < 4; ++j)
            acc[i][j] = (f32x4){0.f, 0.f, 0.f, 0.f};

    STAGE_A(0); STAGE_B(0); STAGE_A(1); STAGE_B(1); STAGE_A(2);
    asm volatile("s_waitcnt vmcnt(6)" ::: "memory");
    __builtin_amdgcn_s_barrier();

#pragma unroll 4
    for (int T = 0; T < GNT; ++T) {
        const int so = (T & 3) * 8192;
        bf16x8 w0, w1, w2, w3, x0, x1, x2, x3;

        // ---- phase 0: W-frags 0-3 x all X ----
        w0 = *(const bf16x8*)&ldsB[so + offW[0]];
        w1 = *(const bf16x8*)&ldsB[so + offW[1]];
        w2 = *(const bf16x8*)&ldsB[so + offW[2]];
        w3 = *(const bf16x8*)&ldsB[so + offW[3]];
        x0 = *(const bf16x8*)&ldsA[so + offX[0]];
        x1 = *(const bf16x8*)&ldsA[so + offX[1]];
        x2 = *(const bf16x8*)&ldsA[so + offX[2]];
        x3 = *(const bf16x8*)&ldsA[so + offX[3]];
        if (T + 2 < GNT) STAGE_B(T + 2);
        __builtin_amdgcn_s_barrier();
        asm volatile("s_waitcnt lgkmcnt(0)" ::: "memory");
        __builtin_amdgcn_sched_barrier(0);
        __builtin_amdgcn_s_setprio(1);
        acc[0][0] = __builtin_amdgcn_mfma_f32_16x16x32_bf16(w0, x0, acc[0][0], 0, 0, 0);
        acc[0][1] = __builtin_amdgcn_mfma_f32_16x16x32_bf16(w0, x1, acc[0][1], 0, 0, 0);
        acc[0][2] = __builtin_amdgcn_mfma_f32_16x16x32_bf16(w0, x2, acc[0][2], 0, 0, 0);
        acc[0][3] = __builtin_amdgcn_mfma_f32_16x16x32_bf16(w0, x3, acc[0][3], 0, 0, 0);
        acc[1][0] = __builtin_amdgcn_mfma_f32_16x16x32_bf16(w1, x0, acc[1][0], 0, 0, 0);
        acc[1][1] = __builtin_amdgcn_mfma_f32_16x16x32_bf16(w1, x1, acc[1][1], 0, 0, 0);
        acc[1][2] = __builtin_amdgcn_mfma_f32_16x16x32_bf16(w1, x2, acc[1][2], 0, 0, 0);
        acc[1][3] = __builtin_amdgcn_mfma_f32_16x16x32_bf16(w1, x3, acc[1][3], 0, 0, 0);
        acc[2][0] = __builtin_amdgcn_mfma_f32_16x16x32_bf16(w2, x0, acc[2][0], 0, 0, 0);
        acc[2][1] = __builtin_amdgcn_mfma_f32_16x16x32_bf16(w2, x1, acc[2][1], 0, 0, 0);
        acc[2][2] = __builtin_amdgcn_mfma_f32_16x16x32_bf16(w2, x2, acc[2][2], 0, 0, 0);
        acc[2][3] = __builtin_amdgcn_mfma_f32_16x16x32_bf16(w2, x3, acc[2][3], 0, 0, 0);
        acc[3][0] = __builtin_amdgcn_mfma_f32_16x16x32_bf16(w3, x0, acc[3][0], 0, 0, 0);
        acc[3][1] = __builtin_amdgcn_mfma_f32_16x16x32_bf16(w3, x1, acc[3][1], 0, 0, 0);
        acc[3][2] = __builtin_amdgcn_mfma_f32_16x16x32_bf16(w3, x2, acc[3][2], 0, 0, 0);
        acc[3][3] = __builtin_amdgcn_mfma_f32_16x16x32_bf16(w3, x3, acc[3][3], 0, 0, 0);
        __builtin_amdgcn_s_setprio(0);
        __builtin_amdgcn_s_barrier();

        // ---- phase 1: W-frags 4-7 x all X ----
        w0 = *(const bf16x8*)&ldsB[so + offW[4]];
        w1 = *(const bf16x8*)&ldsB[so + offW[5]];
        w2 = *(const bf16x8*)&ldsB[so + offW[6]];
        w3 = *(const bf16x8*)&ldsB[so + offW[7]];
        if (T + 3 < GNT) STAGE_A(T + 3);
        __builtin_amdgcn_s_barrier();
        asm volatile("s_waitcnt lgkmcnt(0)" ::: "memory");
        __builtin_amdgcn_sched_barrier(0);
        __builtin_amdgcn_s_setprio(1);
        acc[4][0] = __builtin_amdgcn_mfma_f32_16x16x32_bf16(w0, x0, acc[4][0], 0, 0, 0);
        acc[4][1] = __builtin_amdgcn_mfma_f32_16x16x32_bf16(w0, x1, acc[4][1], 0, 0, 0);
        acc[4][2] = __builtin_amdgcn_mfma_f32_16x16x32_bf16(w0, x2, acc[4][2], 0, 0, 0);
        acc[4][3] = __builtin_amdgcn_mfma_f32_16x16x32_bf16(w0, x3, acc[4][3], 0, 0, 0);
        acc[5][0] = __builtin_amdgcn_mfma_f32_16x16x32_bf16(w1, x0, acc[5][0], 0, 0, 0);
        acc[5][1] = __builtin_amdgcn_mfma_f32_16x16x32_bf16(w1, x1, acc[5][1], 0, 0, 0);
        acc[5][2] = __builtin_amdgcn_mfma_f32_16x16x32_bf16(w1, x2, acc[5][2], 0, 0, 0);
        acc[5][3] = __builtin_amdgcn_mfma_f32_16x16x32_bf16(w1, x3, acc[5][3], 0, 0, 0);
        acc[6][0] = __builtin_amdgcn_mfma_f32_16x16x32_bf16(w2, x0, acc[6][0], 0, 0, 0);
        acc[6][1] = __builtin_amdgcn_mfma_f32_16x16x32_bf16(w2, x1, acc[6][1], 0, 0, 0);
        acc[6][2] = __builtin_amdgcn_mfma_f32_16x16x32_bf16(w2, x2, acc[6][2], 0, 0, 0);
        acc[6][3] = __builtin_amdgcn_mfma_f32_16x16x32_bf16(w2, x3, acc[6][3], 0, 0, 0);
        acc[7][0] = __builtin_amdgcn_mfma_f32_16x16x32_bf16(w3, x0, acc[7][0], 0, 0, 0);
        acc[7][1] = __builtin_amdgcn_mfma_f32_16x16x32_bf16(w3, x1, acc[7][1], 0, 0, 0);
        acc[7][2] = __builtin_amdgcn_mfma_f32_16x16x32_bf16(w3, x2, acc[7][2], 0, 0, 0);
        acc[7][3] = __builtin_amdgcn_mfma_f32_16x16x32_bf16(w3, x3, acc[7][3], 0, 0, 0);
        __builtin_amdgcn_s_setprio(0);
        if (T < GNT - 3)      { asm volatile("s_waitcnt vmcnt(6)" ::: "memory"); }
        else if (T == GNT - 3){ asm volatile("s_waitcnt vmcnt(4)" ::: "memory"); }
        else if (T == GNT - 2){ asm volatile("s_waitcnt vmcnt(0)" ::: "memory"); }
        __builtin_amdgcn_s_barrier();
    }

    // ---- SLIM epilogue: pack + row-major uint2 store only ----
    const int gc0 = bcol + wr * 128 + kc * 4;
    const int mr0 = brow + wc * 64 + lr;
#pragma unroll
    for (int f = 0; f < 8; ++f) {
#pragma unroll
        for (int n = 0; n < 4; ++n) {
            unsigned u0 = f2bf(acc[f][n][0]), u1 = f2bf(acc[f][n][1]);
            unsigned u2 = f2bf(acc[f][n][2]), u3 = f2bf(acc[f][n][3]);
            uint2 pk; pk.x = u0 | (u1 << 16); pk.y = u2 | (u3 << 16);
            *reinterpret_cast<uint2*>(&C[(size_t)(mr0 + n * 16) * N + gc0 + f * 16]) = pk;
        }
    }
#undef STAGE_A
#undef STAGE_B
}

// ---------------- fused LN-stats + LN + LSTM pointwise ----------------
// one block (256 thr) per batch row; gates loaded ONCE into registers,
// stats block-reduced, then registers reused for the gate math.
__global__ __launch_bounds__(256) void ln_lstm(
    const unsigned short* __restrict__ i2h,   // [B,4H] bf16 (rounded, no bias)
    const unsigned short* __restrict__ h2h,   // [B,4H] bf16 (rounded, no bias)
    const float* __restrict__ cx,
    const float* __restrict__ b_hh,
    const float* __restrict__ g_ih, const float* __restrict__ be_ih,
    const float* __restrict__ g_hh, const float* __restrict__ be_hh,
    const float* __restrict__ g_ho, const float* __restrict__ be_ho,
    float* __restrict__ hy, float* __restrict__ cy, int H)
{
    const int b = blockIdx.x;
    const int t = threadIdx.x;
    const int lane = t & 63;
    const int wave = t >> 6;
    const int H4 = 4 * H;
    const int h0 = t * 4;

    const unsigned short* xi = i2h + (size_t)b * H4;
    const unsigned short* xh = h2h + (size_t)b * H4;

    __shared__ float red[4][4];
    __shared__ float red2[4][2];

    // ---- load gates to registers + accumulate stats (h2h gets f32 bias) ----
    float exi[4][4], exh[4][4];
    float si = 0.f, qi = 0.f, sh = 0.f, qh = 0.f;
#pragma unroll
    for (int q = 0; q < 4; ++q) {
        const int j = q * H + h0;
        ushort4 vi = *reinterpret_cast<const ushort4*>(&xi[j]);
        ushort4 vh = *reinterpret_cast<const ushort4*>(&xh[j]);
        float4 bb = *reinterpret_cast<const float4*>(&b_hh[j]);
        exi[q][0] = bf2f(vi.x); exi[q][1] = bf2f(vi.y);
        exi[q][2] = bf2f(vi.z); exi[q][3] = bf2f(vi.w);
        exh[q][0] = bf2f(vh.x) + bb.x; exh[q][1] = bf2f(vh.y) + bb.y;
        exh[q][2] = bf2f(vh.z) + bb.z; exh[q][3] = bf2f(vh.w) + bb.w;
#pragma unroll
        for (int k = 0; k < 4; ++k) {
            si += exi[q][k]; qi = __builtin_fmaf(exi[q][k], exi[q][k], qi);
            sh += exh[q][k]; qh = __builtin_fmaf(exh[q][k], exh[q][k], qh);
        }
    }
    si = wred(si); qi = wred(qi); sh = wred(sh); qh = wred(qh);
    if (lane == 0) { red[wave][0] = si; red[wave][1] = qi; red[wave][2] = sh; red[wave][3] = qh; }
    __syncthreads();
    float Si = red[0][0] + red[1][0] + red[2][0] + red[3][0];
    float Qi = red[0][1] + red[1][1] + red[2][1] + red[3][1];
    float Sh = red[0][2] + red[1][2] + red[2][2] + red[3][2];
    float Qh = red[0][3] + red[1][3] + red[2][3] + red[3][3];
    const float inv4H = 1.0f / (float)H4;
    const float mI = Si * inv4H, mH = Sh * inv4H;
    const float rI = rsqrtf(Qi * inv4H - mI * mI + LN_EPS);
    const float rH = rsqrtf(Qh * inv4H - mH * mH + LN_EPS);

    // ---- gate math (registers reused, params streamed) ----
    float gate[4][4];
#pragma unroll
    for (int q = 0; q < 4; ++q) {
        const int j = q * H + h0;
        float4 gi = *reinterpret_cast<const float4*>(&g_ih[j]);
        float4 bi = *reinterpret_cast<const float4*>(&be_ih[j]);
        float4 gh = *reinterpret_cast<const float4*>(&g_hh[j]);
        float4 bh = *reinterpret_cast<const float4*>(&be_hh[j]);
        gate[q][0] = (exi[q][0] - mI) * rI * gi.x + bi.x + (exh[q][0] - mH) * rH * gh.x + bh.x;
        gate[q][1] = (exi[q][1] - mI) * rI * gi.y + bi.y + (exh[q][1] - mH) * rH * gh.y + bh.y;
        gate[q][2] = (exi[q][2] - mI) * rI * gi.z + bi.z + (exh[q][2] - mH) * rH * gh.z + bh.z;
        gate[q][3] = (exi[q][3] - mI) * rI * gi.w + bi.w + (exh[q][3] - mH) * rH * gh.w + bh.w;
    }

    float4 cxv = *reinterpret_cast<const float4*>(&cx[(size_t)b * H + h0]);
    float cvals[4] = {cxv.x, cxv.y, cxv.z, cxv.w};
    float tv[4], ov[4];
    float s2 = 0.f, q2 = 0.f;
    float4 cyv;
#pragma unroll
    for (int k = 0; k < 4; ++k) {
        float c = sigf(gate[1][k]) * cvals[k] + sigf(gate[0][k]) * tanh_fast(gate[3][k]);
        ((float*)&cyv)[k] = c;
        float tc = tanh_fast(c);
        tv[k] = tc; ov[k] = sigf(gate[2][k]);
        s2 += tc; q2 += tc * tc;
    }
    *reinterpret_cast<float4*>(&cy[(size_t)b * H + h0]) = cyv;

    s2 = wred(s2); q2 = wred(q2);
    if (lane == 0) { red2[wave][0] = s2; red2[wave][1] = q2; }
    __syncthreads();
    float S2 = red2[0][0] + red2[1][0] + red2[2][0] + red2[3][0];
    float Q2 = red2[0][1] + red2[1][1] + red2[2][1] + red2[3][1];
    const float invH = 1.0f / (float)H;
    float mt = S2 * invH;
    float rt = rsqrtf(Q2 * invH - mt * mt + LN_EPS);

    float4 go = *reinterpret_cast<const float4*>(&g_ho[h0]);
    float4 bo = *reinterpret_cast<const float4*>(&be_ho[h0]);
    float4 hyv;
    hyv.x = ov[0] * ((tv[0] - mt) * rt * go.x + bo.x);
    hyv.y = ov[1] * ((tv[1] - mt) * rt * go.y + bo.y);
    hyv.z = ov[2] * ((tv[2] - mt) * rt * go.z + bo.z);
    hyv.w = ov[3] * ((tv[3] - mt) * rt * go.w + bo.w);
    *reinterpret_cast<float4*>(&hy[(size_t)b * H + h0]) = hyv;
}

// ---------------- launcher ----------------
extern "C" void kernel_launch(void* const* d_in, const int* in_sizes, int n_in,
                              void* d_out, int out_size, void* d_ws, size_t ws_size,
                              hipStream_t stream) {
    const float* inputs  = (const float*)d_in[0];
    const float* hx      = (const float*)d_in[1];
    const float* cx      = (const float*)d_in[2];
    const float* w_ih    = (const float*)d_in[3];
    const float* w_hh    = (const float*)d_in[4];
    const float* b_hh    = (const float*)d_in[5];
    const float* g_ih    = (const float*)d_in[6];
    const float* beta_ih = (const float*)d_in[7];
    const float* g_hh    = (const float*)d_in[8];
    const float* beta_hh = (const float*)d_in[9];
    const float* g_ho    = (const float*)d_in[10];
    const float* beta_ho = (const float*)d_in[11];

    const int H  = in_sizes[10];            // 1024
    const int B  = in_sizes[1] / H;         // 4096
    const int D  = in_sizes[0] / B;         // 1024
    const int H4 = 4 * H;

    uint8_t* ws = (uint8_t*)d_ws;
    size_t off = 0;
    short* Abf  = (short*)(ws + off); off += (size_t)B * D * 2;
    short* Hbf  = (short*)(ws + off); off += (size_t)B * H * 2;
    short* Wih  = (short*)(ws + off); off += (size_t)H4 * D * 2;
    short* Whh  = (short*)(ws + off); off += (size_t)H4 * H * 2;
    unsigned short* i2hb = (unsigned short*)(ws + off); off += (size_t)B * H4 * 2;
    unsigned short* h2hb = (unsigned short*)(ws + off); off += (size_t)B * H4 * 2;

    float* hy  = (float*)d_out;
    float* cyo = (float*)d_out + (size_t)B * H;

    // 1) all casts in one launch
    {
        const int n0 = (B * D) / 4, n1 = (B * H) / 4, n2 = (H4 * D) / 4, n3 = (H4 * H) / 4;
        const int tot = n0 + n1 + n2 + n3;
        cast_all<<<(tot + 255) / 256, 256, 0, stream>>>(
            (const float4*)inputs, (ushort4*)Abf, n0,
            (const float4*)hx,     (ushort4*)Hbf, n1,
            (const float4*)w_ih,   (ushort4*)Wih, n2,
            (const float4*)w_hh,   (ushort4*)Whh, n3);
    }

    // 2) both GEMMs, slim pack-only epilogue
    {
        dim3 grid(H4 / 256, B / 256, 2);
        gemm8p<<<grid, 512, 0, stream>>>(Abf, Wih, i2hb, Hbf, Whh, h2hb, H4, D);
    }

    // 3) fused stats + LN + LSTM
    ln_lstm<<<B, 256, 0, stream>>>(i2hb, h2hb, cx, b_hh,
                                   g_ih, beta_ih, g_hh, beta_hh, g_ho, beta_ho,
                                   hy, cyo, H);
}